// Round 1
// baseline (2234.017 us; speedup 1.0000x reference)
//
#include <hip/hip_runtime.h>
#include <cstddef>

#define BB   16384
#define TT_  100
#define FF   64
#define K4   20
#define HH   5
#define NOUT 3

__device__ __forceinline__ float sigf(float x) {
    // 1/(1+e^-x); rcp ~1ulp, fine vs threshold
    return __builtin_amdgcn_rcpf(1.0f + __expf(-x));
}
__device__ __forceinline__ float tanhf_fast(float x) {
    // tanh(x) = 1 - 2/(e^{2x}+1); safe at +/-inf
    return 1.0f - 2.0f * __builtin_amdgcn_rcpf(__expf(2.0f * x) + 1.0f);
}

// ===========================================================================
// K1: projection GEMM.  z[t][b][k] = x[b,t,:] @ W1[:,k] + b1[k]
// Layout [T][B][20] so K2 (lane=batch) reads coalesced.
// One wave / block: 8 batches x 8 timesteps per chunk, row-per-lane.
// W1^T broadcast from LDS (same addr all lanes -> free).  x reads are
// strided across lanes but each lane's row (256B = 4 lines) is reused by
// 4 consecutive float4 reads -> L1 absorbs (16KB working set / wave).
// Memory-bound target: 419MB read + 131MB write ~ 87us floor.
// ===========================================================================
__global__ __launch_bounds__(64, 2) void proj_kernel(
    const float* __restrict__ x, const float* __restrict__ W1,
    const float* __restrict__ b1, float* __restrict__ z)
{
    __shared__ float sWT[K4][FF];      // W1^T
    const int lane = threadIdx.x;
    const int tloc = lane >> 3;        // 0..7 timestep within chunk
    const int g    = lane & 7;         // batch within block
    const int b    = blockIdx.x * 8 + g;

#pragma unroll
    for (int w = 0; w < 20; ++w) {
        int i = w * 64 + lane;         // i = f*20 + k
        sWT[i % K4][i / K4] = W1[i];
    }
    float bz[K4];
#pragma unroll
    for (int k = 0; k < K4; ++k) bz[k] = b1[k];
    __syncthreads();

    const float4* xrow = (const float4*)(x + ((size_t)b * TT_ + tloc) * FF);
    float4 xa[16], xb[16];
#pragma unroll
    for (int i = 0; i < 16; ++i) xa[i] = xrow[i];

    for (int c = 0; c < 13; ++c) {     // 12 full chunks of 8t + tail of 4t
        // prefetch next chunk (in flight during compute below)
        if (c < 12) {
            int tn = c * 8 + 8 + tloc; if (tn > TT_ - 1) tn = TT_ - 1;
            const float4* p = (const float4*)(x + ((size_t)b * TT_ + tn) * FF);
#pragma unroll
            for (int i = 0; i < 16; ++i) xb[i] = p[i];
        }
        const int t = c * 8 + tloc;
        float zr[K4];
#pragma unroll
        for (int k = 0; k < K4; ++k) { // fully unrolled: zr[] indices static
            float a0 = bz[k], a1 = 0.f, a2 = 0.f, a3 = 0.f;
#pragma unroll
            for (int p = 0; p < 4; ++p) {   // 4 independent chains for ILP
                const float4 w0 = *(const float4*)&sWT[k][p * 16 + 0];
                const float4 w1 = *(const float4*)&sWT[k][p * 16 + 4];
                const float4 w2 = *(const float4*)&sWT[k][p * 16 + 8];
                const float4 w3 = *(const float4*)&sWT[k][p * 16 + 12];
                const float4 x0 = xa[p * 4 + 0], x1 = xa[p * 4 + 1];
                const float4 x2 = xa[p * 4 + 2], x3 = xa[p * 4 + 3];
                a0 = fmaf(x0.w, w0.w, fmaf(x0.z, w0.z, fmaf(x0.y, w0.y, fmaf(x0.x, w0.x, a0))));
                a1 = fmaf(x1.w, w1.w, fmaf(x1.z, w1.z, fmaf(x1.y, w1.y, fmaf(x1.x, w1.x, a1))));
                a2 = fmaf(x2.w, w2.w, fmaf(x2.z, w2.z, fmaf(x2.y, w2.y, fmaf(x2.x, w2.x, a2))));
                a3 = fmaf(x3.w, w3.w, fmaf(x3.z, w3.z, fmaf(x3.y, w3.y, fmaf(x3.x, w3.x, a3))));
            }
            zr[k] = (a0 + a1) + (a2 + a3);
        }
        if (t < TT_) {
            float4* zp = (float4*)(z + ((size_t)t * BB + b) * K4);
#pragma unroll
            for (int q = 0; q < 5; ++q)
                zp[q] = make_float4(zr[4 * q], zr[4 * q + 1], zr[4 * q + 2], zr[4 * q + 3]);
        }
#pragma unroll
        for (int i = 0; i < 16; ++i) xa[i] = xb[i];
    }
}

// ===========================================================================
// K2: recurrence, ONE BATCH PER LANE.  No cross-lane ops in the chain:
// h1/h2/h3/c1/c2/c3 for all 5 units live in lane-private registers.
// 256 waves total (1/CU) -> waves_per_eu(1,1) unlocks the 512-VGPR budget:
// U1,W2,U2 (300 floats) stay in registers; W3,U3,b2,b3 broadcast from LDS
// (same addr all lanes, conflict-free).  z prefetched 1 timestep ahead,
// coalesced ([T][B][20], L3-resident after K1).
// Per timestep: ~500 FMA (20 independent dots -> deep ILP) + ~400 gate ops,
// issue-bound ~2k cyc -> ~85-100us.
// ===========================================================================
__global__ __launch_bounds__(64) __attribute__((amdgpu_waves_per_eu(1, 1)))
void rec_kernel(
    const float* __restrict__ z,
    const float* __restrict__ U1,
    const float* __restrict__ W2, const float* __restrict__ U2, const float* __restrict__ b2,
    const float* __restrict__ W3, const float* __restrict__ U3, const float* __restrict__ b3,
    const float* __restrict__ Wd, const float* __restrict__ bd,
    float* __restrict__ out)
{
    __shared__ float sW3T[K4][8];      // [k][d=0..4]; [k][5] = b2[k]
    __shared__ float sU3T[K4][8];      // [k][d=0..4]; [k][5] = b3[k]
    const int lane = threadIdx.x;
    const size_t b = (size_t)blockIdx.x * 64 + lane;

    for (int i = lane; i < 100; i += 64) {      // i = d*20 + k
        sW3T[i % K4][i / K4] = W3[i];
        sU3T[i % K4][i / K4] = U3[i];
    }
    if (lane < K4) { sW3T[lane][5] = b2[lane]; sU3T[lane][5] = b3[lane]; }
    __syncthreads();

    // 300 weight floats in registers (same values in every lane; broadcast loads)
    float u1r[HH][K4], w2r[HH][K4], u2r[HH][K4];
#pragma unroll
    for (int d = 0; d < HH; ++d)
#pragma unroll
        for (int k = 0; k < K4; ++k) {
            u1r[d][k] = U1[d * K4 + k];
            w2r[d][k] = W2[d * K4 + k];
            u2r[d][k] = U2[d * K4 + k];
        }

    float h1[HH] = {}, h2[HH] = {}, h3[HH] = {};
    float c1[HH] = {}, c2[HH] = {}, c3[HH] = {};

    float4 zc[5];
    {
        const float4* zp = (const float4*)(z + b * K4);   // t = 0
#pragma unroll
        for (int q = 0; q < 5; ++q) zc[q] = zp[q];
    }

#pragma unroll 2
    for (int t = 0; t < TT_; ++t) {
        // prefetch next timestep's z (latency hidden under this step's compute)
        float4 zn[5];
        if (t < TT_ - 1) {
            const float4* zp = (const float4*)(z + ((size_t)(t + 1) * BB + b) * K4);
#pragma unroll
            for (int q = 0; q < 5; ++q) zn[q] = zp[q];
        }
        float zt[K4];
#pragma unroll
        for (int q = 0; q < 5; ++q) {
            zt[4 * q + 0] = zc[q].x; zt[4 * q + 1] = zc[q].y;
            zt[4 * q + 2] = zc[q].z; zt[4 * q + 3] = zc[q].w;
        }

        float zl[K4];
        // ---- layer 1: z already includes xW1+b1
#pragma unroll
        for (int k = 0; k < K4; ++k) {
            float a = zt[k];
#pragma unroll
            for (int d = 0; d < HH; ++d) a = fmaf(h1[d], u1r[d][k], a);
            zl[k] = a;
        }
#pragma unroll
        for (int u = 0; u < HH; ++u) {
            const float iv = sigf(zl[u]),        fv = sigf(zl[5 + u]);
            const float gv = tanhf_fast(zl[10 + u]), ov = sigf(zl[15 + u]);
            c1[u] = fmaf(fv, c1[u], iv * gv);
            h1[u] = ov * tanhf_fast(c1[u]);
        }
        // ---- layer 2
#pragma unroll
        for (int k = 0; k < K4; ++k) {
            float a = sW3T[k][5];   // b2[k]
#pragma unroll
            for (int d = 0; d < HH; ++d) a = fmaf(h1[d], w2r[d][k], a);
#pragma unroll
            for (int d = 0; d < HH; ++d) a = fmaf(h2[d], u2r[d][k], a);
            zl[k] = a;
        }
#pragma unroll
        for (int u = 0; u < HH; ++u) {
            const float iv = sigf(zl[u]),        fv = sigf(zl[5 + u]);
            const float gv = tanhf_fast(zl[10 + u]), ov = sigf(zl[15 + u]);
            c2[u] = fmaf(fv, c2[u], iv * gv);
            h2[u] = ov * tanhf_fast(c2[u]);
        }
        // ---- layer 3 (weights broadcast from LDS)
#pragma unroll
        for (int k = 0; k < K4; ++k) {
            const float4 w3q = *(const float4*)&sW3T[k][0];
            const float4 u3q = *(const float4*)&sU3T[k][0];
            float a = sU3T[k][5];   // b3[k]
            a = fmaf(h2[0], w3q.x, a); a = fmaf(h2[1], w3q.y, a);
            a = fmaf(h2[2], w3q.z, a); a = fmaf(h2[3], w3q.w, a);
            a = fmaf(h2[4], sW3T[k][4], a);
            a = fmaf(h3[0], u3q.x, a); a = fmaf(h3[1], u3q.y, a);
            a = fmaf(h3[2], u3q.z, a); a = fmaf(h3[3], u3q.w, a);
            a = fmaf(h3[4], sU3T[k][4], a);
            zl[k] = a;
        }
#pragma unroll
        for (int u = 0; u < HH; ++u) {
            const float iv = sigf(zl[u]),        fv = sigf(zl[5 + u]);
            const float gv = tanhf_fast(zl[10 + u]), ov = sigf(zl[15 + u]);
            c3[u] = fmaf(fv, c3[u], iv * gv);
            h3[u] = ov * tanhf_fast(c3[u]);
        }

        if (t < TT_ - 1) {
#pragma unroll
            for (int q = 0; q < 5; ++q) zc[q] = zn[q];
        }
    }

    // ---- output head
#pragma unroll
    for (int o = 0; o < NOUT; ++o) {
        float s = bd[o];
#pragma unroll
        for (int d = 0; d < HH; ++d) s = fmaf(h3[d], Wd[d * NOUT + o], s);
        out[b * NOUT + o] = s;
    }
}

extern "C" void kernel_launch(void* const* d_in, const int* in_sizes, int n_in,
                              void* d_out, int out_size, void* d_ws, size_t ws_size,
                              hipStream_t stream) {
    const float* x   = (const float*)d_in[0];
    const float* W1  = (const float*)d_in[1];
    const float* U1  = (const float*)d_in[2];
    const float* b1  = (const float*)d_in[3];
    const float* W2  = (const float*)d_in[4];
    const float* U2  = (const float*)d_in[5];
    const float* b2  = (const float*)d_in[6];
    const float* W3  = (const float*)d_in[7];
    const float* U3  = (const float*)d_in[8];
    const float* b3  = (const float*)d_in[9];
    const float* Wd  = (const float*)d_in[10];
    const float* bdp = (const float*)d_in[11];
    float* out = (float*)d_out;

    // workspace: z in [T][B][20] fp32 = 131.1 MB (ws is ~1.6GB per harness poison)
    float* zws = (float*)d_ws;

    proj_kernel<<<BB / 8, 64, 0, stream>>>(x, W1, b1, zws);
    rec_kernel<<<BB / 64, 64, 0, stream>>>(zws, U1, W2, U2, b2, W3, U3, b3, Wd, bdp, out);
}

// Round 2
// 1017.933 us; speedup vs baseline: 2.1947x; 2.1947x over previous
//
#include <hip/hip_runtime.h>
#include <cstddef>

#define BB   16384
#define TT_  100
#define FF   64
#define K4   20
#define HH   5
#define NOUT 3

__device__ __forceinline__ float sigf(float x) {
    // 1/(1+e^-x); rcp ~1ulp, fine vs threshold
    return __builtin_amdgcn_rcpf(1.0f + __expf(-x));
}
__device__ __forceinline__ float tanhf_fast(float x) {
    // tanh(x) = 1 - 2/(e^{2x}+1); safe at +/-inf
    return 1.0f - 2.0f * __builtin_amdgcn_rcpf(__expf(2.0f * x) + 1.0f);
}
template <int IMM>
__device__ __forceinline__ float swz(float v) {
    return __int_as_float(__builtin_amdgcn_ds_swizzle(__float_as_int(v), IMM));
}

// ===========================================================================
// K1: projection.  z[t][k][b] = x[b,t,:] @ W1[:,k] + b1[k]
//
// Block = 256 thr = 4 waves, one timestep (blockIdx.y), 64 batches
// (blockIdx.x).  4 lanes per (b,t) row: load instr i covers float4s
// i*4+s -> each quad reads 64B CONTIGUOUS per instruction (16 full lines
// per wave-instr; no reliance on L1 retention -> kills round-1's 4.3x
// over-fetch).  Each lane: partial dot over its 16 f (W1 broadcast from
// LDS, 16-lane-dup addresses), quad butterfly reduce via ds_swizzle.
// Store layout [T][20][B]: per store instr, 16 consecutive b = one full
// 64B chunk per k-row (4 rows/instr) -> kills round-1's 2.9x write
// amplification (partial-sector RMW).
// 102,400 waves -> BW-bound target ~ (419+131)MB / 6.3TBps ~ 90-110 us.
// ===========================================================================
__global__ __launch_bounds__(256) void proj_kernel(
    const float* __restrict__ x, const float* __restrict__ W1,
    const float* __restrict__ b1, float* __restrict__ z)
{
    __shared__ float sW[FF * K4];          // [f][k], rows 80B (16B-aligned)
    const int tid = threadIdx.x;
#pragma unroll
    for (int j = 0; j < 5; ++j) sW[j * 256 + tid] = W1[j * 256 + tid];
    __syncthreads();

    const int wv   = tid >> 6;
    const int lane = tid & 63;
    const int q    = lane >> 2;            // row (batch) within wave
    const int s    = lane & 3;             // quad sub-lane
    const int t    = blockIdx.y;
    const int b    = (blockIdx.x << 6) + (wv << 4) + q;

    // coalesced row load: instr i covers row bytes [i*64, i*64+64) per quad
    const float4* rowp = (const float4*)(x + ((size_t)b * TT_ + t) * FF);
    float4 xv[4];
#pragma unroll
    for (int i = 0; i < 4; ++i) xv[i] = rowp[i * 4 + s];

    float zp[K4];
#pragma unroll
    for (int k = 0; k < K4; ++k) zp[k] = 0.f;

    auto accum = [&](float xs, const float* wr) {
#pragma unroll
        for (int k4 = 0; k4 < 5; ++k4) {
            const float4 wq = *(const float4*)(wr + k4 * 4);
            zp[k4 * 4 + 0] = fmaf(xs, wq.x, zp[k4 * 4 + 0]);
            zp[k4 * 4 + 1] = fmaf(xs, wq.y, zp[k4 * 4 + 1]);
            zp[k4 * 4 + 2] = fmaf(xs, wq.z, zp[k4 * 4 + 2]);
            zp[k4 * 4 + 3] = fmaf(xs, wq.w, zp[k4 * 4 + 3]);
        }
    };
#pragma unroll
    for (int i = 0; i < 4; ++i) {
        const int f0 = (i * 4 + s) * 4;    // this lane's 4 f for chunk i
        accum(xv[i].x, &sW[(f0 + 0) * K4]);
        accum(xv[i].y, &sW[(f0 + 1) * K4]);
        accum(xv[i].z, &sW[(f0 + 2) * K4]);
        accum(xv[i].w, &sW[(f0 + 3) * K4]);
    }

    // quad butterfly reduce (lanes s^1, s^2 within quad)
#pragma unroll
    for (int k = 0; k < K4; ++k) {
        float v = zp[k];
        v += swz<0x041F>(v);               // xor 1
        v += swz<0x081F>(v);               // xor 2
        zp[k] = v;
    }

    // lane s writes k = s*5..s*5+4; per instr: 4 k-rows x 64B full chunks
#pragma unroll
    for (int j = 0; j < 5; ++j) {
        const int k = s * 5 + j;
        z[((size_t)t * K4 + k) * BB + b] = zp[k] + b1[k];
    }
}

// ===========================================================================
// K2: recurrence, one batch per lane (no cross-lane ops in the chain).
// ALL weights in LDS, read as lane-uniform float4 broadcasts
// (conflict-free, ~32 ds_read_b128/t) -> register footprint ~130 VGPR,
// no spill risk at any cap (round-1 failure mode).
// z read [T][20][B]: 20 coalesced dword loads per t (256B/instr),
// prefetched 1 timestep ahead (~2k cyc cover vs ~500cyc L3 latency).
// 256 waves (1/CU, 1 SIMD busy): issue-bound ~950 VALU x 2cyc ~ 2k cyc/t
// -> ~90-120 us.
// ===========================================================================
__global__ __launch_bounds__(64) __attribute__((amdgpu_waves_per_eu(1, 2)))
void rec_kernel(
    const float* __restrict__ z,
    const float* __restrict__ U1,
    const float* __restrict__ W2, const float* __restrict__ U2, const float* __restrict__ b2,
    const float* __restrict__ W3, const float* __restrict__ U3, const float* __restrict__ b3,
    const float* __restrict__ Wd, const float* __restrict__ bd,
    float* __restrict__ out)
{
    __shared__ float sU1[HH][K4];          // U1[d][k]
    __shared__ float sM2[10][K4];          // rows 0-4 = W2, 5-9 = U2
    __shared__ float sM3[10][K4];          // rows 0-4 = W3, 5-9 = U3
    __shared__ float sb2[K4], sb3[K4];

    const int lane = threadIdx.x;
    const size_t b = (size_t)blockIdx.x * 64 + lane;

    // cooperative stage: 500 floats
    for (int i = lane; i < 100; i += 64) {
        sU1[0][i]  = U1[i];
        sM2[0][i]  = W2[i];
        sM2[5][i]  = U2[i];
        sM3[0][i]  = W3[i];
        sM3[5][i]  = U3[i];
    }
    if (lane < K4) { sb2[lane] = b2[lane]; sb3[lane] = b3[lane]; }
    __syncthreads();

    float h1[HH] = {}, h2[HH] = {}, h3[HH] = {};
    float c1[HH] = {}, c2[HH] = {}, c3[HH] = {};

    // z[t][k][b] scalar coalesced loads, double-buffered in registers
    float zc[K4], zn[K4];
#pragma unroll
    for (int k = 0; k < K4; ++k) zc[k] = z[(size_t)k * BB + b];   // t = 0

#pragma unroll 1
    for (int t = 0; t < TT_; ++t) {
        // issue next-t loads early; land during this step's ~2k cyc compute
        if (t < TT_ - 1) {
#pragma unroll
            for (int k = 0; k < K4; ++k)
                zn[k] = z[((size_t)(t + 1) * K4 + k) * BB + b];
        }

        float zl[K4];
        // ---- layer 1: zl = z (has xW1+b1) + h1 @ U1
#pragma unroll
        for (int k = 0; k < K4; ++k) zl[k] = zc[k];
#pragma unroll
        for (int d = 0; d < HH; ++d) {
            const float hd = h1[d];
#pragma unroll
            for (int k4 = 0; k4 < 5; ++k4) {
                const float4 w = *(const float4*)&sU1[d][k4 * 4];
                zl[k4 * 4 + 0] = fmaf(hd, w.x, zl[k4 * 4 + 0]);
                zl[k4 * 4 + 1] = fmaf(hd, w.y, zl[k4 * 4 + 1]);
                zl[k4 * 4 + 2] = fmaf(hd, w.z, zl[k4 * 4 + 2]);
                zl[k4 * 4 + 3] = fmaf(hd, w.w, zl[k4 * 4 + 3]);
            }
        }
#pragma unroll
        for (int u = 0; u < HH; ++u) {
            const float iv = sigf(zl[u]),          fv = sigf(zl[5 + u]);
            const float gv = tanhf_fast(zl[10 + u]), ov = sigf(zl[15 + u]);
            c1[u] = fmaf(fv, c1[u], iv * gv);
            h1[u] = ov * tanhf_fast(c1[u]);
        }

        // ---- layer 2: zl = b2 + [h1;h2] @ [W2;U2]
#pragma unroll
        for (int k = 0; k < K4; ++k) zl[k] = sb2[k];
#pragma unroll
        for (int d = 0; d < 10; ++d) {
            const float hd = (d < HH) ? h1[d] : h2[d - HH];
#pragma unroll
            for (int k4 = 0; k4 < 5; ++k4) {
                const float4 w = *(const float4*)&sM2[d][k4 * 4];
                zl[k4 * 4 + 0] = fmaf(hd, w.x, zl[k4 * 4 + 0]);
                zl[k4 * 4 + 1] = fmaf(hd, w.y, zl[k4 * 4 + 1]);
                zl[k4 * 4 + 2] = fmaf(hd, w.z, zl[k4 * 4 + 2]);
                zl[k4 * 4 + 3] = fmaf(hd, w.w, zl[k4 * 4 + 3]);
            }
        }
#pragma unroll
        for (int u = 0; u < HH; ++u) {
            const float iv = sigf(zl[u]),          fv = sigf(zl[5 + u]);
            const float gv = tanhf_fast(zl[10 + u]), ov = sigf(zl[15 + u]);
            c2[u] = fmaf(fv, c2[u], iv * gv);
            h2[u] = ov * tanhf_fast(c2[u]);
        }

        // ---- layer 3: zl = b3 + [h2;h3] @ [W3;U3]
#pragma unroll
        for (int k = 0; k < K4; ++k) zl[k] = sb3[k];
#pragma unroll
        for (int d = 0; d < 10; ++d) {
            const float hd = (d < HH) ? h2[d] : h3[d - HH];
#pragma unroll
            for (int k4 = 0; k4 < 5; ++k4) {
                const float4 w = *(const float4*)&sM3[d][k4 * 4];
                zl[k4 * 4 + 0] = fmaf(hd, w.x, zl[k4 * 4 + 0]);
                zl[k4 * 4 + 1] = fmaf(hd, w.y, zl[k4 * 4 + 1]);
                zl[k4 * 4 + 2] = fmaf(hd, w.z, zl[k4 * 4 + 2]);
                zl[k4 * 4 + 3] = fmaf(hd, w.w, zl[k4 * 4 + 3]);
            }
        }
#pragma unroll
        for (int u = 0; u < HH; ++u) {
            const float iv = sigf(zl[u]),          fv = sigf(zl[5 + u]);
            const float gv = tanhf_fast(zl[10 + u]), ov = sigf(zl[15 + u]);
            c3[u] = fmaf(fv, c3[u], iv * gv);
            h3[u] = ov * tanhf_fast(c3[u]);
        }

        if (t < TT_ - 1) {
#pragma unroll
            for (int k = 0; k < K4; ++k) zc[k] = zn[k];
        }
    }

    // ---- output head
#pragma unroll
    for (int o = 0; o < NOUT; ++o) {
        float s = bd[o];
#pragma unroll
        for (int d = 0; d < HH; ++d) s = fmaf(h3[d], Wd[d * NOUT + o], s);
        out[b * NOUT + o] = s;
    }
}

extern "C" void kernel_launch(void* const* d_in, const int* in_sizes, int n_in,
                              void* d_out, int out_size, void* d_ws, size_t ws_size,
                              hipStream_t stream) {
    const float* x   = (const float*)d_in[0];
    const float* W1  = (const float*)d_in[1];
    const float* U1  = (const float*)d_in[2];
    const float* b1  = (const float*)d_in[3];
    const float* W2  = (const float*)d_in[4];
    const float* U2  = (const float*)d_in[5];
    const float* b2  = (const float*)d_in[6];
    const float* W3  = (const float*)d_in[7];
    const float* U3  = (const float*)d_in[8];
    const float* b3  = (const float*)d_in[9];
    const float* Wd  = (const float*)d_in[10];
    const float* bdp = (const float*)d_in[11];
    float* out = (float*)d_out;

    // workspace: z in [T][20][B] fp32 = 131.1 MB
    float* zws = (float*)d_ws;

    dim3 pgrid(BB / 64, TT_);
    proj_kernel<<<pgrid, 256, 0, stream>>>(x, W1, b1, zws);
    rec_kernel<<<BB / 64, 64, 0, stream>>>(zws, U1, W2, U2, b2, W3, U3, b3, Wd, bdp, out);
}